// Round 1
// baseline (652.196 us; speedup 1.0000x reference)
//
#include <hip/hip_runtime.h>
#include <cstdint>
#include <cstddef>

// TrimodalCrossAttention: seq_len=1 => softmax==1 => attention i reduces to
//   att_i(kv) = kv @ (Wo_i@Wv_i)^T + (Wo_i@bv_i + bo_i)
// Everything folds into: out = relu([g|d|c] @ A + bias_h) @ W2^T + b2
// with A [768,512] built from W1 and Wf_i = Wo_i@Wv_i.

typedef __attribute__((ext_vector_type(8))) short short8;
typedef __attribute__((ext_vector_type(4))) float float4v;

__device__ __forceinline__ unsigned short f2bf(float f) {
  union { float f; unsigned u; } v; v.f = f;
  unsigned r = v.u + 0x7FFFu + ((v.u >> 16) & 1u);   // round-to-nearest-even
  return (unsigned short)(r >> 16);
}

// ---------------- P0: Wf[i] = Wo[i] @ Wv[i]  (6x 256x256x256 fp32) ----------
__global__ __launch_bounds__(256) void k_wf(const float* __restrict__ Wo,
                                            const float* __restrict__ Wv,
                                            float* __restrict__ Wf) {
  int b = blockIdx.x;              // 0..1535
  int i = b >> 8, m = b & 255;
  int n = threadIdx.x;
  const float* wo = Wo + i * 65536 + m * 256;   // row m (broadcast across lanes)
  const float* wv = Wv + i * 65536 + n;         // column n (coalesced)
  float acc = 0.f;
#pragma unroll 4
  for (int k = 0; k < 256; ++k) acc += wo[k] * wv[k * 256];
  Wf[i * 65536 + m * 256 + n] = acc;
}

// ---------------- P0b: bf sums: bfs[p] = bf_{2p} + bf_{2p+1} ----------------
__global__ __launch_bounds__(256) void k_bf(const float* __restrict__ Wo,
                                            const float* __restrict__ bv,
                                            const float* __restrict__ bo,
                                            float* __restrict__ bfs) {
  int p = blockIdx.x;              // 0:g(att0,1) 1:d(att2,3) 2:c(att4,5)
  int m = threadIdx.x;
  int a = 2 * p, b2i = 2 * p + 1;
  float acc = bo[a * 256 + m] + bo[b2i * 256 + m];
  for (int k = 0; k < 256; ++k) {
    acc += Wo[a * 65536 + m * 256 + k] * bv[a * 256 + k];
    acc += Wo[b2i * 65536 + m * 256 + k] * bv[b2i * 256 + k];
  }
  bfs[p * 256 + m] = acc;
}

// ---------------- P1: fold A[k][n] and write XOR-swizzled bf16 --------------
// ATS layout: per k-step tile t (32 k's = 32KB), 16B unit (n,kq):
//   unit = n*4 + (kq ^ (n&3)), element j8 inside unit. Matches main b-frag reads.
__global__ __launch_bounds__(256) void k_fold(const float* __restrict__ W1,
                                              const float* __restrict__ Wf,
                                              unsigned short* __restrict__ ATS) {
  int b = blockIdx.x;              // 0..1535
  int n = b & 511, p = b >> 9;     // p: 0=g,1=d,2=c  (k-part)
  int kk = threadIdx.x;
  int fA, oA, fB, oB;
  if (p == 0)      { fA = 2; oA = 256; fB = 4; oB = 512; }   // dg, cg
  else if (p == 1) { fA = 0; oA = 0;   fB = 5; oB = 512; }   // gd, cd
  else             { fA = 1; oA = 0;   fB = 3; oB = 256; }   // gc, dc
  const float* w1n = W1 + n * 768;
  float val = w1n[p * 256 + kk];                 // identity (residual) term
  const float* wfa = Wf + fA * 65536 + kk;
  const float* wfb = Wf + fB * 65536 + kk;
#pragma unroll 4
  for (int j = 0; j < 256; ++j) {
    val += w1n[oA + j] * wfa[j * 256];
    val += w1n[oB + j] * wfb[j * 256];
  }
  int k = p * 256 + kk;
  int t = k >> 5, kq = (k >> 3) & 3, j8 = k & 7;
  int unit = n * 4 + (kq ^ (n & 3));
  ATS[t * 16384 + unit * 8 + j8] = f2bf(val);
}

// ---------------- P1b: bias_h[n] = b1[n] + sum_k W1[n][k]*bfs[k] ------------
__global__ __launch_bounds__(256) void k_biash(const float* __restrict__ W1,
                                               const float* __restrict__ b1,
                                               const float* __restrict__ bfs,
                                               float* __restrict__ bias_h) {
  int n = blockIdx.x;              // 0..511
  int kk = threadIdx.x;
  const float* w1n = W1 + n * 768;
  float v = w1n[kk] * bfs[kk] + w1n[256 + kk] * bfs[256 + kk] +
            w1n[512 + kk] * bfs[512 + kk];
  __shared__ float red[256];
  red[kk] = v; __syncthreads();
  for (int s = 128; s > 0; s >>= 1) { if (kk < s) red[kk] += red[kk + s]; __syncthreads(); }
  if (kk == 0) bias_h[n] = red[0] + b1[n];
}

// ---------------- P2: W2 -> bf16, chunk-permuted for stage-2 ----------------
// W2p[(c*256 + n)*64 + kp] = W2[n][(c + 8*(kp>>4))*16 + (kp&15)]
__global__ __launch_bounds__(256) void k_w2(const float* __restrict__ W2,
                                            unsigned short* __restrict__ W2p) {
  int id = blockIdx.x * 256 + threadIdx.x;       // 0..131071
  int cpos = id >> 14;
  int n = (id >> 6) & 255;
  int kp = id & 63;
  int t = kp >> 4, ci = kp & 15;
  W2p[id] = f2bf(W2[n * 512 + (cpos + 8 * t) * 16 + ci]);
}

// ---------------- Main fused kernel -----------------------------------------
// Block: 128 rows x full N=512 hidden, 512 threads (8 waves).
// Stage 1: hidden = relu(X@A + bias_h), wave tile 64x128 (4x8 16x16x32 MFMA).
// Stage 2: out = hidden @ W2p + b2, chunked 64-wide hidden exchange via LDS.
__global__ __launch_bounds__(512, 2) void k_main(
    const float* __restrict__ G, const float* __restrict__ D,
    const float* __restrict__ C, const unsigned short* __restrict__ ATS,
    const float* __restrict__ bias_h, const unsigned short* __restrict__ W2p,
    const float* __restrict__ b2, float* __restrict__ Out) {
  __shared__ unsigned short ats[16384];     // 32 KB swizzled A tile (512n x 32k)
  __shared__ unsigned short xt[128][40];    // 10 KB X tile bf16 (+8 pad -> 2-way free)
  __shared__ unsigned short hid[128][72];   // 18 KB hidden chunk (64 + 8 pad)

  const int tid = threadIdx.x;
  const int lane = tid & 63, wave = tid >> 6;
  const int l15 = lane & 15, lq = lane >> 4;
  const int m0 = blockIdx.x * 128;

  const int wm = wave >> 2, wn = wave & 3;  // stage-1 wave tile: rows wm*64, cols wn*128

  float4v acc1[4][8];
#pragma unroll
  for (int j = 0; j < 8; ++j) {
    float bh = bias_h[wn * 128 + j * 16 + l15];
#pragma unroll
    for (int i = 0; i < 4; ++i) acc1[i][j] = (float4v){bh, bh, bh, bh};
  }

  const int xrow = tid >> 2, xseg = tid & 3;

  for (int kt = 0; kt < 24; ++kt) {
    const int k0 = kt * 32;
    const float* Xsrc = (k0 < 256) ? G : (k0 < 512) ? D : C;
    const int kc = k0 & 255;

    // stage X: 128x32 fp32 -> bf16 into LDS (one ds_write_b128 per thread)
    const float* xp = Xsrc + (size_t)(m0 + xrow) * 256 + kc + xseg * 8;
    float4v f0 = *(const float4v*)xp;
    float4v f1 = *(const float4v*)(xp + 4);
    short8 xv;
    xv[0] = f2bf(f0[0]); xv[1] = f2bf(f0[1]); xv[2] = f2bf(f0[2]); xv[3] = f2bf(f0[3]);
    xv[4] = f2bf(f1[0]); xv[5] = f2bf(f1[1]); xv[6] = f2bf(f1[2]); xv[7] = f2bf(f1[3]);
    *(short8*)&xt[xrow][xseg * 8] = xv;

    // stage A tile: 32 KB async global->LDS, 16B/lane x 4 iters
    const char* gsrc = (const char*)ATS + (size_t)kt * 32768;
#pragma unroll
    for (int it = 0; it < 4; ++it) {
      __builtin_amdgcn_global_load_lds(
          (const __attribute__((address_space(1))) unsigned int*)(gsrc + it * 8192 + tid * 16),
          (__attribute__((address_space(3))) unsigned int*)((char*)ats + it * 8192 + tid * 16),
          16, 0, 0);
    }
    __syncthreads();

    short8 a[4];
#pragma unroll
    for (int i = 0; i < 4; ++i)
      a[i] = *(const short8*)&xt[wm * 64 + i * 16 + l15][lq * 8];
#pragma unroll
    for (int j = 0; j < 8; ++j) {
      int n = wn * 128 + j * 16 + l15;
      int unit = n * 4 + (lq ^ (n & 3));
      short8 bfrag = *(const short8*)&ats[unit * 8];
#pragma unroll
      for (int i = 0; i < 4; ++i)
        acc1[i][j] = __builtin_amdgcn_mfma_f32_16x16x32_bf16(a[i], bfrag, acc1[i][j], 0, 0, 0);
    }
    __syncthreads();
  }

  // ---- stage 2: out[128][256] += relu(hidden) @ W2 ----
  const int om = wave >> 2, on = wave & 3;  // out wave tile: rows om*64, cols on*64
  float4v acc2[4][4];
#pragma unroll
  for (int j = 0; j < 4; ++j) {
    float bb = b2[on * 64 + j * 16 + l15];
#pragma unroll
    for (int i = 0; i < 4; ++i) acc2[i][j] = (float4v){bb, bb, bb, bb};
  }

  for (int cpos = 0; cpos < 8; ++cpos) {
    // every wave writes its local n-tile j==cpos (global tile cpos+8*wn) -> chunk col wn*16
#pragma unroll
    for (int i = 0; i < 4; ++i) {
#pragma unroll
      for (int r = 0; r < 4; ++r) {
        float v = acc1[i][cpos][r];
        v = v > 0.f ? v : 0.f;                      // relu
        hid[wm * 64 + i * 16 + lq * 4 + r][wn * 16 + l15] = f2bf(v);
      }
    }
    __syncthreads();
#pragma unroll
    for (int ks = 0; ks < 2; ++ks) {
      short8 a2[4];
#pragma unroll
      for (int i = 0; i < 4; ++i)
        a2[i] = *(const short8*)&hid[om * 64 + i * 16 + l15][ks * 32 + lq * 8];
#pragma unroll
      for (int j = 0; j < 4; ++j) {
        int n = on * 64 + j * 16 + l15;
        const unsigned short* bp = W2p + ((size_t)(cpos * 256 + n) * 64 + ks * 32 + lq * 8);
        short8 bfrag = *(const short8*)bp;
#pragma unroll
        for (int i = 0; i < 4; ++i)
          acc2[i][j] = __builtin_amdgcn_mfma_f32_16x16x32_bf16(a2[i], bfrag, acc2[i][j], 0, 0, 0);
      }
    }
    __syncthreads();
  }

  // epilogue: fp32 stores, 64B row segments per 16-lane group
#pragma unroll
  for (int i = 0; i < 4; ++i) {
#pragma unroll
    for (int r = 0; r < 4; ++r) {
      int row = m0 + om * 64 + i * 16 + lq * 4 + r;
      float* op = Out + (size_t)row * 256 + on * 64 + l15;
#pragma unroll
      for (int j = 0; j < 4; ++j) op[j * 16] = acc2[i][j][r];
    }
  }
}

// ---------------- launcher ---------------------------------------------------
extern "C" void kernel_launch(void* const* d_in, const int* in_sizes, int n_in,
                              void* d_out, int out_size, void* d_ws, size_t ws_size,
                              hipStream_t stream) {
  const float* G  = (const float*)d_in[0];
  const float* D  = (const float*)d_in[1];
  const float* C  = (const float*)d_in[2];
  // d_in[3]=Wq, d_in[4]=Wk unused: softmax over 1 key == 1 identically
  const float* Wv = (const float*)d_in[5];
  // d_in[6]=bq, d_in[7]=bk unused
  const float* bv = (const float*)d_in[8];
  const float* Wo = (const float*)d_in[9];
  const float* bo = (const float*)d_in[10];
  const float* W1 = (const float*)d_in[11];
  const float* b1 = (const float*)d_in[12];
  const float* W2 = (const float*)d_in[13];
  const float* b2 = (const float*)d_in[14];

  char* ws = (char*)d_ws;
  float* Wf           = (float*)(ws);                       // 1,572,864 B
  float* bfs          = (float*)(ws + 1572864);             //     3,072 B
  float* bias_h       = (float*)(ws + 1575936);             //     2,048 B
  unsigned short* ATS = (unsigned short*)(ws + 1577984);    //   786,432 B
  unsigned short* W2p = (unsigned short*)(ws + 2364416);    //   262,144 B  (~2.6 MB total)
  float* Out = (float*)d_out;

  hipLaunchKernelGGL(k_wf,    dim3(1536), dim3(256), 0, stream, Wo, Wv, Wf);
  hipLaunchKernelGGL(k_bf,    dim3(3),    dim3(256), 0, stream, Wo, bv, bo, bfs);
  hipLaunchKernelGGL(k_fold,  dim3(1536), dim3(256), 0, stream, W1, Wf, ATS);
  hipLaunchKernelGGL(k_biash, dim3(512),  dim3(256), 0, stream, W1, b1, bfs, bias_h);
  hipLaunchKernelGGL(k_w2,    dim3(512),  dim3(256), 0, stream, W2, W2p);
  hipLaunchKernelGGL(k_main,  dim3(1024), dim3(512), 0, stream, G, D, C, ATS, bias_h, W2p, b2, Out);
}